// Round 7
// baseline (520.464 us; speedup 1.0000x reference)
//
#include <hip/hip_runtime.h>
#include <hip/hip_bf16.h>
#include <math.h>

#define H 128

typedef __bf16 bf16x8 __attribute__((ext_vector_type(8)));
typedef float f32x4 __attribute__((ext_vector_type(4)));
typedef __hip_bfloat16 bf16;

__device__ __forceinline__ bf16x8 ldb8(const bf16* p) {
  return *(const bf16x8*)(const void*)p;
}
__device__ __forceinline__ float fsig(float x) {
  return __fdividef(1.f, 1.f + __expf(-x));
}
__device__ __forceinline__ float ftanh(float x) {
  float x2 = fminf(fmaxf(2.f * x, -80.f), 80.f);
  float t = __expf(x2);
  return __fdividef(t - 1.f, t + 1.f);
}

// fused setup: [0,nb1) init_h ; [nb1,nb1+nb2) cvt whh ; [nb1+nb2,...) G
__global__ __launch_bounds__(256) void k_setup(const float* __restrict__ x,
                                               bf16* __restrict__ hb,
                                               const float* __restrict__ whh,
                                               bf16* __restrict__ whhb,
                                               const float* __restrict__ W,
                                               const float* __restrict__ wih,
                                               bf16* __restrict__ G,
                                               int N, int nb1, int nb2) {
  int b = blockIdx.x;
  if (b < nb1) {
    int i = b * 256 + threadIdx.x;
    if (i < N * H) {
      int f = i & (H - 1);
      int n = i >> 7;
      hb[i] = __float2bfloat16((f < 64) ? x[n * 64 + f] : 0.f);
    }
    return;
  }
  b -= nb1;
  if (b < nb2) {
    int i = b * 256 + threadIdx.x;
    if (i < 3 * H * H) whhb[i] = __float2bfloat16(whh[i]);
    return;
  }
  b -= nb2;
  int idx = b * 256 + threadIdx.x;
  if (idx >= 3 * 3 * H * H) return;
  int l = idx / (3 * H * H);
  int r = idx % (3 * H * H);
  int j = r >> 7;
  int k = r & (H - 1);
  const float4* a = (const float4*)(wih + (size_t)j * H);
  const float4* bb = (const float4*)(W + (size_t)l * H * H + (size_t)k * H);
  float s = 0.f;
#pragma unroll
  for (int q = 0; q < 32; q++) {
    float4 av = a[q], bv = bb[q];
    s += av.x * bv.x + av.y * bv.y + av.z * bv.z + av.w * bv.w;
  }
  G[idx] = __float2bfloat16(s);
}

// ---------- CSR build ----------
__global__ __launch_bounds__(256) void k_count(const int* __restrict__ dst,
                                               int* __restrict__ deg, int E) {
  int e = blockIdx.x * 256 + threadIdx.x;
  if (e < E) atomicAdd(&deg[dst[e]], 1);
}

__global__ __launch_bounds__(256) void k_bsum(const int* __restrict__ deg,
                                              int* __restrict__ bsums, int N) {
  __shared__ int ws[4];
  int t = threadIdx.x;
  int i = blockIdx.x * 256 + t;
  int v = (i < N) ? deg[i] : 0;
#pragma unroll
  for (int d = 1; d < 64; d <<= 1) v += __shfl_xor(v, d, 64);
  if ((t & 63) == 0) ws[t >> 6] = v;
  __syncthreads();
  if (t == 0) bsums[blockIdx.x] = ws[0] + ws[1] + ws[2] + ws[3];
}

__global__ __launch_bounds__(256) void k_bscan(int* __restrict__ bsums, int nb) {
  __shared__ int ws[4];
  int t = threadIdx.x;
  int lane = t & 63, w = t >> 6;
  int v = (t < nb) ? bsums[t] : 0;
  int s = v;
#pragma unroll
  for (int d = 1; d < 64; d <<= 1) {
    int u = __shfl_up(s, d, 64);
    if (lane >= d) s += u;
  }
  if (lane == 63) ws[w] = s;
  __syncthreads();
  int woff = 0;
  if (w >= 1) woff += ws[0];
  if (w >= 2) woff += ws[1];
  if (w >= 3) woff += ws[2];
  if (t < nb) bsums[t] = woff + s - v;
}

__global__ __launch_bounds__(256) void k_scan2(const int* __restrict__ deg,
                                               const int* __restrict__ bsums,
                                               int* __restrict__ rowptr,
                                               int* __restrict__ cursor,
                                               int N, int E) {
  __shared__ int ws[4];
  int t = threadIdx.x;
  int lane = t & 63, w = t >> 6;
  int i = blockIdx.x * 256 + t;
  int v = (i < N) ? deg[i] : 0;
  int s = v;
#pragma unroll
  for (int d = 1; d < 64; d <<= 1) {
    int u = __shfl_up(s, d, 64);
    if (lane >= d) s += u;
  }
  if (lane == 63) ws[w] = s;
  __syncthreads();
  int woff = 0;
  if (w >= 1) woff += ws[0];
  if (w >= 2) woff += ws[1];
  if (w >= 3) woff += ws[2];
  int excl = bsums[blockIdx.x] + woff + s - v;
  if (i < N) { rowptr[i] = excl; cursor[i] = excl; }
  if (i == 0) rowptr[N] = E;
}

__global__ __launch_bounds__(256) void k_fill(const int* __restrict__ src,
                                              const int* __restrict__ dst,
                                              int* __restrict__ cursor,
                                              int* __restrict__ csr_src, int E) {
  int e = blockIdx.x * 256 + threadIdx.x;
  if (e < E) {
    int pos = atomicAdd(&cursor[dst[e]], 1);
    csr_src[pos] = src[e];
  }
}

// ---------- fused layer: gather A = segsum(h[src]) into LDS, then GRU ----------
// block = 512 threads = 8 waves, owns 32 rows.
// gather lane layout: s = lane>>3 edge slot (8 rows/instr in flight),
//                     c = lane&7 col-group (32 B per lane)
#define ASTRIDE 136   // 128 + 8 bf16 pad
__global__ __launch_bounds__(512) void k_layer(const bf16* __restrict__ hbin,
                                               bf16* __restrict__ hbout,
                                               const bf16* __restrict__ Gl,
                                               const bf16* __restrict__ whhb,
                                               const float* __restrict__ bih,
                                               const float* __restrict__ bhh,
                                               const int* __restrict__ rowptr,
                                               const int* __restrict__ csr_src,
                                               int N) {
  __shared__ bf16 As[32 * ASTRIDE];
  __shared__ bf16 Hs[32 * ASTRIDE];
  int t = threadIdx.x;
  int w = t >> 6;
  int lane = t & 63;
  int row0 = blockIdx.x * 32;

  // ---- stage own h rows (coalesced) ----
  {
    int rl = t >> 4;
    int c = t & 15;
    int row = row0 + rl; if (row > N - 1) row = N - 1;
    bf16x8 v = ldb8(hbin + (size_t)row * H + c * 8);
    *(bf16x8*)(&Hs[rl * ASTRIDE + c * 8]) = v;
  }

  // ---- gather phase: 8 slots x 8 colgroups, 2-way unrolled ----
  {
    int s = lane >> 3;
    int c = lane & 7;
    int co = c * 16;               // bf16 offset of this lane's 32 B chunk
    for (int rr = 0; rr < 4; rr++) {
      int rl = w * 4 + rr;
      int row = row0 + rl;
      float acc[16];
#pragma unroll
      for (int j = 0; j < 16; j++) acc[j] = 0.f;
      if (row < N) {
        int b = rowptr[row], e = rowptr[row + 1];
        int i = b + s;
        for (; i + 8 < e; i += 16) {
          int s0 = csr_src[i];
          int s1 = csr_src[i + 8];
          const bf16* p0 = hbin + (size_t)s0 * H + co;
          const bf16* p1 = hbin + (size_t)s1 * H + co;
          bf16x8 v0a = ldb8(p0), v0b = ldb8(p0 + 8);
          bf16x8 v1a = ldb8(p1), v1b = ldb8(p1 + 8);
#pragma unroll
          for (int j = 0; j < 8; j++) {
            acc[j]     += (float)v0a[j] + (float)v1a[j];
            acc[j + 8] += (float)v0b[j] + (float)v1b[j];
          }
        }
        if (i < e) {
          int s0 = csr_src[i];
          const bf16* p0 = hbin + (size_t)s0 * H + co;
          bf16x8 v0a = ldb8(p0), v0b = ldb8(p0 + 8);
#pragma unroll
          for (int j = 0; j < 8; j++) {
            acc[j]     += (float)v0a[j];
            acc[j + 8] += (float)v0b[j];
          }
        }
      }
      // reduce across the 8 slots (lane bits 3..5)
#pragma unroll
      for (int j = 0; j < 16; j++) {
        acc[j] += __shfl_xor(acc[j], 8, 64);
        acc[j] += __shfl_xor(acc[j], 16, 64);
        acc[j] += __shfl_xor(acc[j], 32, 64);
      }
      if (s == 0) {
        bf16x8 oa, ob;
#pragma unroll
        for (int j = 0; j < 8; j++) { oa[j] = (__bf16)acc[j]; ob[j] = (__bf16)acc[j + 8]; }
        *(bf16x8*)(&As[rl * ASTRIDE + co]) = oa;
        *(bf16x8*)(&As[rl * ASTRIDE + co + 8]) = ob;
      }
    }
  }
  __syncthreads();

  // ---- GRU phase (A and h from LDS) ----
  int r = lane & 15, quad = lane >> 4, laneK = quad * 8;
  int col = w * 16 + r;

  f32x4 aIR[2], aIZ[2], aIN[2], aHR[2], aHZ[2], aHN[2];
#pragma unroll
  for (int q = 0; q < 2; q++) {
    aIR[q] = (f32x4){0.f, 0.f, 0.f, 0.f};
    aIZ[q] = aIR[q]; aIN[q] = aIR[q];
    aHR[q] = aIR[q]; aHZ[q] = aIR[q]; aHN[q] = aIR[q];
  }

  size_t wo0 = (size_t)(0 * H + col) * H;
  size_t wo1 = (size_t)(1 * H + col) * H;
  size_t wo2 = (size_t)(2 * H + col) * H;

#pragma unroll
  for (int kb = 0; kb < 4; kb++) {
    int ko = kb * 32 + laneK;
    bf16x8 a0 = *(const bf16x8*)(&As[r * ASTRIDE + ko]);
    bf16x8 a1 = *(const bf16x8*)(&As[(16 + r) * ASTRIDE + ko]);
    bf16x8 h0 = *(const bf16x8*)(&Hs[r * ASTRIDE + ko]);
    bf16x8 h1 = *(const bf16x8*)(&Hs[(16 + r) * ASTRIDE + ko]);
    bf16x8 gr = ldb8(Gl + wo0 + ko);
    aIR[0] = __builtin_amdgcn_mfma_f32_16x16x32_bf16(a0, gr, aIR[0], 0, 0, 0);
    aIR[1] = __builtin_amdgcn_mfma_f32_16x16x32_bf16(a1, gr, aIR[1], 0, 0, 0);
    bf16x8 gz = ldb8(Gl + wo1 + ko);
    aIZ[0] = __builtin_amdgcn_mfma_f32_16x16x32_bf16(a0, gz, aIZ[0], 0, 0, 0);
    aIZ[1] = __builtin_amdgcn_mfma_f32_16x16x32_bf16(a1, gz, aIZ[1], 0, 0, 0);
    bf16x8 gn = ldb8(Gl + wo2 + ko);
    aIN[0] = __builtin_amdgcn_mfma_f32_16x16x32_bf16(a0, gn, aIN[0], 0, 0, 0);
    aIN[1] = __builtin_amdgcn_mfma_f32_16x16x32_bf16(a1, gn, aIN[1], 0, 0, 0);
    bf16x8 ur = ldb8(whhb + wo0 + ko);
    aHR[0] = __builtin_amdgcn_mfma_f32_16x16x32_bf16(h0, ur, aHR[0], 0, 0, 0);
    aHR[1] = __builtin_amdgcn_mfma_f32_16x16x32_bf16(h1, ur, aHR[1], 0, 0, 0);
    bf16x8 uz = ldb8(whhb + wo1 + ko);
    aHZ[0] = __builtin_amdgcn_mfma_f32_16x16x32_bf16(h0, uz, aHZ[0], 0, 0, 0);
    aHZ[1] = __builtin_amdgcn_mfma_f32_16x16x32_bf16(h1, uz, aHZ[1], 0, 0, 0);
    bf16x8 un = ldb8(whhb + wo2 + ko);
    aHN[0] = __builtin_amdgcn_mfma_f32_16x16x32_bf16(h0, un, aHN[0], 0, 0, 0);
    aHN[1] = __builtin_amdgcn_mfma_f32_16x16x32_bf16(h1, un, aHN[1], 0, 0, 0);
  }

  float bir = bih[col], biz = bih[H + col], bin = bih[2 * H + col];
  float bhr = bhh[col], bhz = bhh[H + col], bhn = bhh[2 * H + col];
#pragma unroll
  for (int q = 0; q < 2; q++) {
#pragma unroll
    for (int i = 0; i < 4; i++) {
      int lrow = q * 16 + quad * 4 + i;
      int row = row0 + lrow;
      if (row < N) {
        float rg = fsig(aIR[q][i] + bir + aHR[q][i] + bhr);
        float zg = fsig(aIZ[q][i] + biz + aHZ[q][i] + bhz);
        float ng = ftanh(aIN[q][i] + bin + rg * (aHN[q][i] + bhn));
        float hold = __bfloat162float(Hs[lrow * ASTRIDE + col]);
        float hp = (1.f - zg) * ng + zg * hold;
        hbout[(size_t)row * H + col] = __float2bfloat16(hp);
      }
    }
  }
}

// out[n,:] = log_softmax(h[n,:] @ lin_w^T + lin_b); one wave per node (bf16 h)
__global__ __launch_bounds__(256) void k_classify(const bf16* __restrict__ h,
                                                  const float* __restrict__ lw,
                                                  const float* __restrict__ lb,
                                                  float* __restrict__ out, int N) {
  int wave = (blockIdx.x * 256 + threadIdx.x) >> 6;
  int lane = threadIdx.x & 63;
  if (wave >= N) return;
  int c = lane & 15;
  int q = lane >> 4;
  const bf16* hr = h + (size_t)wave * H + q * 32;
  const float* wr = lw + c * H + q * 32;
  float p = 0.f;
#pragma unroll
  for (int k = 0; k < 32; k += 8) {
    bf16x8 a = ldb8(hr + k);
    float4 w0 = *(const float4*)(wr + k);
    float4 w1 = *(const float4*)(wr + k + 4);
    p += (float)a[0] * w0.x + (float)a[1] * w0.y + (float)a[2] * w0.z + (float)a[3] * w0.w;
    p += (float)a[4] * w1.x + (float)a[5] * w1.y + (float)a[6] * w1.z + (float)a[7] * w1.w;
  }
  p += __shfl_xor(p, 16, 64);
  p += __shfl_xor(p, 32, 64);
  float z = p + lb[c];
  float mx = z;
#pragma unroll
  for (int d = 1; d < 16; d <<= 1) mx = fmaxf(mx, __shfl_xor(mx, d, 64));
  float e = expf(z - mx);
  float s = e;
#pragma unroll
  for (int d = 1; d < 16; d <<= 1) s += __shfl_xor(s, d, 64);
  if (q == 0) out[(size_t)wave * 16 + c] = z - mx - logf(s);
}

extern "C" void kernel_launch(void* const* d_in, const int* in_sizes, int n_in,
                              void* d_out, int out_size, void* d_ws, size_t ws_size,
                              hipStream_t stream) {
  const float* x   = (const float*)d_in[0];
  const int*   ei  = (const int*)d_in[1];
  const float* W   = (const float*)d_in[2];
  const float* wih = (const float*)d_in[3];
  const float* whh = (const float*)d_in[4];
  const float* bih = (const float*)d_in[5];
  const float* bhh = (const float*)d_in[6];
  const float* lw  = (const float*)d_in[7];
  const float* lb  = (const float*)d_in[8];
  float* out = (float*)d_out;

  int N = in_sizes[0] / 64;   // 50000
  int E = in_sizes[1] / 2;    // 800000
  const int* src = ei;
  const int* dst = ei + E;

  size_t NH = (size_t)N * H;
  bf16* hb0  = (bf16*)d_ws;                  // [N,H] bf16 h ping
  bf16* hb1  = hb0 + NH;                     // [N,H] bf16 h pong
  bf16* Gb   = hb1 + NH;                     // [3][3H,H]
  bf16* whhb = Gb + 3 * 3 * H * H;           // [3H,H]
  int* deg     = (int*)(whhb + 3 * H * H);
  int* rowptr  = deg + N;                    // N+1
  int* cursor  = rowptr + N + 1;             // N
  int* bsums   = cursor + N;                 // <=256
  int* csr_src = bsums + 256;                // E

  int nb_e  = (E + 255) / 256;
  int nb_n  = (N + 255) / 256;

  int nb1 = (int)((NH + 255) / 256);
  int nb2 = (3 * H * H + 255) / 256;
  int nb3 = (3 * 3 * H * H + 255) / 256;
  k_setup<<<nb1 + nb2 + nb3, 256, 0, stream>>>(x, hb0, whh, whhb, W, wih, Gb,
                                               N, nb1, nb2);

  hipMemsetAsync(deg, 0, (size_t)N * sizeof(int), stream);
  k_count<<<nb_e, 256, 0, stream>>>(dst, deg, E);
  k_bsum<<<nb_n, 256, 0, stream>>>(deg, bsums, N);
  k_bscan<<<1, 256, 0, stream>>>(bsums, nb_n);
  k_scan2<<<nb_n, 256, 0, stream>>>(deg, bsums, rowptr, cursor, N, E);
  k_fill<<<nb_e, 256, 0, stream>>>(src, dst, cursor, csr_src, E);

  int nb_layer = (N + 31) / 32;
  bf16* hbp[2] = {hb0, hb1};
  for (int l = 0; l < 3; l++) {
    bf16* hin  = hbp[l & 1];
    bf16* hout = hbp[(l + 1) & 1];
    k_layer<<<nb_layer, 512, 0, stream>>>(hin, hout,
                                          Gb + (size_t)l * 3 * H * H, whhb,
                                          bih, bhh, rowptr, csr_src, N);
  }

  k_classify<<<(N + 3) / 4, 256, 0, stream>>>(hb1, lw, lb, out, N);
}